// Round 17
// baseline (129.463 us; speedup 1.0000x reference)
//
#include <hip/hip_runtime.h>
#include <hip/hip_bf16.h>
#include <stdint.h>

typedef __attribute__((ext_vector_type(4))) float f32x4;
typedef __attribute__((ext_vector_type(8))) short bf16x8;
typedef __attribute__((ext_vector_type(4))) unsigned short us4;
typedef unsigned short ushort_t;
typedef unsigned long long u64;

#define LOG2E 1.44269504088896340f

__device__ __forceinline__ unsigned short f2bf(float x){
  union { float f; uint32_t u; } v; v.f = x;
  uint32_t u = v.u + 0x7fffu + ((v.u >> 16) & 1u);
  return (unsigned short)(u >> 16);
}

__device__ __forceinline__ void gld16(const void* g, void* l){
  __builtin_amdgcn_global_load_lds(
      (const __attribute__((address_space(1))) unsigned int*)g,
      (__attribute__((address_space(3))) unsigned int*)l, 16, 0, 0);
}

// ---------------- prep: fp32 -> bf16 (q,k,v,Wq,Wk,Wv,Wo) -------------------------
__global__ void prep_all(const float4* __restrict__ q, const float4* __restrict__ k,
                         const float4* __restrict__ v, const float4* __restrict__ wq,
                         const float4* __restrict__ wk, const float4* __restrict__ wv,
                         const float4* __restrict__ wo, ushort_t* __restrict__ dst){
  int i = blockIdx.x * 256 + threadIdx.x;   // 0 .. 4194303 (float4 units)
  const float4* src; int base;
  if      (i < 1048576){ src = q;  base = 0; }
  else if (i < 2097152){ src = k;  base = 1048576; }
  else if (i < 3145728){ src = v;  base = 2097152; }
  else if (i < 3407872){ src = wq; base = 3145728; }
  else if (i < 3670016){ src = wk; base = 3407872; }
  else if (i < 3932160){ src = wv; base = 3670016; }
  else                 { src = wo; base = 3932160; }
  float4 f = src[i - base];
  us4 o; o.x = f2bf(f.x); o.y = f2bf(f.y); o.z = f2bf(f.z); o.w = f2bf(f.w);
  ((us4*)dst)[i] = o;
}

// ---------------- fused QKV projection GEMM (z selects q/k/v; z==3 packs mask) ---
// Vt must NOT alias anything read by z=0/1/2 blocks (intra-launch race, R5 bug):
// it lives in d_out, which is scratch until gemm_out.
__global__ void gemm_qkv(const ushort_t* __restrict__ qb, const ushort_t* __restrict__ kb,
                         const ushort_t* __restrict__ vb, const ushort_t* __restrict__ wqb,
                         const ushort_t* __restrict__ wkb, const ushort_t* __restrict__ wvb,
                         ushort_t* __restrict__ Qh, ushort_t* __restrict__ Kh,
                         ushort_t* __restrict__ Vt, float qscale,
                         const int4* __restrict__ mask, u64* __restrict__ mb){
  __shared__ ushort_t smem[16384];   // As[2][4096] | Bs[2][4096]; reused as T post-loop
#define AsQ(c) (smem + (c)*4096)
#define BsQ(c) (smem + 8192 + (c)*4096)
  const int z = blockIdx.z;
  if (z == 3){
    // mask pack: 256 blocks * 256 thr * 2 words = 131072 u64 words
    int bid2 = blockIdx.x + (blockIdx.y << 5);
    #pragma unroll
    for (int rep = 0; rep < 2; rep++){
      int w = bid2 * 512 + rep * 256 + threadIdx.x;
      const int4* p = mask + (size_t)w * 16;
      u64 bits = 0;
      #pragma unroll
      for (int j = 0; j < 16; j++){
        int4 m = p[j];
        bits |= (u64)(m.x != 0) << (j*4);
        bits |= (u64)(m.y != 0) << (j*4+1);
        bits |= (u64)(m.z != 0) << (j*4+2);
        bits |= (u64)(m.w != 0) << (j*4+3);
      }
      mb[w] = bits;
    }
    return;
  }
  const ushort_t* A = (z == 0) ? qb  : (z == 1) ? kb  : vb;
  const ushort_t* B = (z == 0) ? wqb : (z == 1) ? wkb : wvb;
  ushort_t*       C = (z == 0) ? Qh  : (z == 1) ? Kh  : Vt;
  const float scale = (z == 0) ? qscale : 1.0f;

  const int tid = threadIdx.x, wave = tid >> 6, lane = tid & 63;
  const int l15 = lane & 15;
  const int m0 = blockIdx.x * 128, n0 = blockIdx.y * 128;
  const int wr = wave >> 1, wc = wave & 1;
  f32x4 acc[4][4] = {};

  const ushort_t* Ag = A + (size_t)(m0 + wave*16 + (lane>>2)) * 1024 + (lane&3)*8;
  const ushort_t* Bg = B + (size_t)(n0 + wave*16 + (lane>>2)) * 1024 + (lane&3)*8;

#define GSTAGE(k0, c) do { \
    gld16(Ag + (k0),         AsQ(c) + wave*512); \
    gld16(Ag + 65536 + (k0), AsQ(c) + (4+wave)*512); \
    gld16(Bg + (k0),         BsQ(c) + wave*512); \
    gld16(Bg + 65536 + (k0), BsQ(c) + (4+wave)*512); } while(0)

  GSTAGE(0, 0);
  int cur = 0;
  for (int k0 = 0; k0 < 1024; k0 += 32){
    __syncthreads();                     // buf[cur] staged (vmcnt drained); prev reads done
    if (k0 < 992) GSTAGE(k0 + 32, cur ^ 1);
    bf16x8 a[4], b[4];
    #pragma unroll
    for (int i = 0; i < 4; i++){
      a[i] = *(const bf16x8*)&AsQ(cur)[(wr*64 + i*16 + l15)*32 + (lane>>4)*8];
      b[i] = *(const bf16x8*)&BsQ(cur)[(wc*64 + i*16 + l15)*32 + (lane>>4)*8];
    }
    __builtin_amdgcn_s_setprio(1);
    #pragma unroll
    for (int i = 0; i < 4; i++)
      #pragma unroll
      for (int j = 0; j < 4; j++)
        acc[i][j] = __builtin_amdgcn_mfma_f32_16x16x32_bf16(a[i], b[j], acc[i][j], 0, 0, 0);
    __builtin_amdgcn_s_setprio(0);
    cur ^= 1;
  }

  if (z < 2){
    #pragma unroll
    for (int i = 0; i < 4; i++){
      #pragma unroll
      for (int j = 0; j < 4; j++){
        #pragma unroll
        for (int r = 0; r < 4; r++){
          int row = m0 + wr*64 + i*16 + (lane>>4)*4 + r;
          int col = n0 + wc*64 + j*16 + l15;
          int bb = row >> 11, s = row & 2047, h = col >> 6, d = col & 63;
          C[((size_t)(bb*16 + h)*2048 + s)*64 + d] = f2bf(acc[i][j][r] * scale);
        }
      }
    }
  } else {
    // transpose epilogue: two 64-col halves through LDS T[64][136]
    ushort_t* T = smem;
    #pragma unroll
    for (int hh = 0; hh < 2; hh++){
      __syncthreads();
      if (wc == hh){
        #pragma unroll
        for (int i = 0; i < 4; i++){
          #pragma unroll
          for (int j = 0; j < 4; j++){
            int n = j*16 + l15;
            int mb2 = wr*64 + i*16 + (lane>>4)*4;
            us4 pk;
            pk.x = f2bf(acc[i][j][0]); pk.y = f2bf(acc[i][j][1]);
            pk.z = f2bf(acc[i][j][2]); pk.w = f2bf(acc[i][j][3]);
            *(us4*)&T[n*136 + mb2] = pk;
          }
        }
      }
      __syncthreads();
      #pragma unroll
      for (int cc = 0; cc < 4; cc++){
        int chunk = cc*256 + tid;
        int n = chunk >> 4, mc = chunk & 15;
        uint4 val = *(uint4*)&T[n*136 + mc*8];
        int col = n0 + hh*64 + n;
        int hcol = col >> 6, d = col & 63;
        int row = m0 + mc*8;
        int bb2 = row >> 11, s = row & 2047;
        *(uint4*)&C[((size_t)(bb2*16 + hcol)*64 + d)*2048 + s] = val;
      }
    }
  }
}

// ---------------- output GEMM: fp32 [M,N] = A[M,K] * W[N,K]^T + bias -------------
// 512 threads / 8 waves (4 m-bands x 2 n-bands, wave tile 32x64).
__global__ __launch_bounds__(512)
void gemm_out(const ushort_t* __restrict__ A, const ushort_t* __restrict__ B,
              float* __restrict__ C, const float* __restrict__ bias){
  __shared__ ushort_t As[2][4096];
  __shared__ ushort_t Bs[2][4096];
  const int tid = threadIdx.x, wave = tid >> 6, lane = tid & 63;
  const int l15 = lane & 15;
  const int m0 = blockIdx.x * 128, n0 = blockIdx.y * 128;
  const int wr = wave >> 1, wc = wave & 1;
  f32x4 acc[2][4] = {};

  const ushort_t* Ag = A + (size_t)(m0 + wave*16 + (lane>>2)) * 1024 + (lane&3)*8;
  const ushort_t* Bg = B + (size_t)(n0 + wave*16 + (lane>>2)) * 1024 + (lane&3)*8;

#define GSTAGE2(k0, c) do { \
    gld16(Ag + (k0), &As[c][wave*512]); \
    gld16(Bg + (k0), &Bs[c][wave*512]); } while(0)

  GSTAGE2(0, 0);
  int cur = 0;
  for (int k0 = 0; k0 < 1024; k0 += 32){
    __syncthreads();
    if (k0 < 992) GSTAGE2(k0 + 32, cur ^ 1);
    bf16x8 a[2], b[4];
    #pragma unroll
    for (int i = 0; i < 2; i++)
      a[i] = *(const bf16x8*)&As[cur][(wr*32 + i*16 + l15)*32 + (lane>>4)*8];
    #pragma unroll
    for (int j = 0; j < 4; j++)
      b[j] = *(const bf16x8*)&Bs[cur][(wc*64 + j*16 + l15)*32 + (lane>>4)*8];
    __builtin_amdgcn_s_setprio(1);
    #pragma unroll
    for (int i = 0; i < 2; i++)
      #pragma unroll
      for (int j = 0; j < 4; j++)
        acc[i][j] = __builtin_amdgcn_mfma_f32_16x16x32_bf16(a[i], b[j], acc[i][j], 0, 0, 0);
    __builtin_amdgcn_s_setprio(0);
    cur ^= 1;
  }

  #pragma unroll
  for (int i = 0; i < 2; i++){
    #pragma unroll
    for (int j = 0; j < 4; j++){
      #pragma unroll
      for (int r = 0; r < 4; r++){
        int row = m0 + wr*32 + i*16 + (lane>>4)*4 + r;
        int col = n0 + wc*64 + j*16 + l15;
        C[(size_t)row * 1024 + col] = acc[i][j][r] + bias[col];
      }
    }
  }
}

// ---------------- fused flash attention (triple-buffer, deferred PV) -------------
// grid: 512 = B(2)*H(16)*(S/128).  8 waves, each owns 16 q-rows (q-tile 128).
// Software pipeline across kv-tiles: body(t) = QK(t) + PV(t-1) + softmax(t) +
// pack(t).  Triple buffer: live tiles {t-1 (PV), t (QK), t+1 (stage)}.
// Mask applied post-exp via sign-shift + integer AND (3 VALU/elem, bit-identical:
// masked -> +0.0 exactly, same as exp2(-1e9)).
__global__ void attn_fused(const ushort_t* __restrict__ Qh, const ushort_t* __restrict__ Kh,
                           const ushort_t* __restrict__ Vt, const u64* __restrict__ MB,
                           ushort_t* __restrict__ AO){
  __shared__ ushort_t Ks[3][4096];  // 64 kv x 64 d, XOR-swizzled rows (128B)
  __shared__ ushort_t Vs[3][4096];  // 64 d  x 64 kv, XOR-swizzled
  __shared__ ushort_t Pb[8][1024];  // per-wave 16 q x 64 kv, XOR-swizzled

  const int tid = threadIdx.x, wave = tid >> 6, lane = tid & 63;
  const int g = lane >> 4, l15 = lane & 15;
  const int wg = ((blockIdx.x & 7) << 6) | (blockIdx.x >> 3);   // XCD swizzle (512=8*64)
  const int qt = wg & 15, h = (wg >> 4) & 15, b = wg >> 8;
  const int q0 = qt * 128;

  const ushort_t* Qb = Qh + ((size_t)(b*16 + h)*2048 + q0) * 64;
  const ushort_t* Kb = Kh + ((size_t)(b*16 + h)*2048) * 64;
  const ushort_t* Vb = Vt + ((size_t)(b*16 + h)*64) * 2048;
  const u64* wp = MB + ((size_t)b*2048 + q0 + wave*16 + l15) * 32;

  bf16x8 qf[2];
  #pragma unroll
  for (int ks = 0; ks < 2; ks++)
    qf[ks] = *(const bf16x8*)&Qb[(wave*16 + l15)*64 + ks*32 + g*8];

  bf16x8 onesb;
  #pragma unroll
  for (int j = 0; j < 8; j++) onesb[j] = (short)0x3F80;

  f32x4 o[4] = {};
  f32x4 osum = {};

  const int srow = lane >> 3;
  const int scol = ((lane & 7) * 16) ^ (srow << 4);
  const ushort_t* Kg = Kb + (size_t)(wave*8 + srow)*64   + (scol >> 1);
  const ushort_t* Vg = Vb + (size_t)(wave*8 + srow)*2048 + (scol >> 1);
  ushort_t* pb = &Pb[wave][0];
  const int xv = (l15 & 7) << 4;
  const int g4 = g * 4;

  // loop-invariant swizzled LDS offsets (ushort / byte units)
  int kaddr[4][2], vaddr[4][2], pwb[4], prb[2];
  #pragma unroll
  for (int nf = 0; nf < 4; nf++){
    int row = nf*16 + l15;
    #pragma unroll
    for (int ks = 0; ks < 2; ks++){
      int cb = (ks*64 + g*16) ^ ((row & 7) << 4);
      kaddr[nf][ks] = row*64 + (cb >> 1);
    }
  }
  #pragma unroll
  for (int df = 0; df < 4; df++){
    int vrow = df*16 + l15;
    #pragma unroll
    for (int c = 0; c < 2; c++){
      int cb = (c*64 + g*16) ^ ((vrow & 7) << 4);
      vaddr[df][c] = vrow*64 + (cb >> 1);
    }
  }
  #pragma unroll
  for (int nf = 0; nf < 4; nf++)
    pwb[nf] = l15*128 + ((nf*32 + g*8) ^ xv);
  #pragma unroll
  for (int c = 0; c < 2; c++)
    prb[c] = l15*128 + ((c*64 + g*16) ^ xv);

#define ASTAGE(t, c) do { \
    gld16(Kg + (size_t)(t)*4096, &Ks[c][wave*512]); \
    gld16(Vg + (t)*64,           &Vs[c][wave*512]); } while(0)

  ASTAGE(0, 0);
  u64 w = wp[0];
  bf16x8 pa[2];           // P fragment of tile t-1 (valid from t>=1)
  int qc = 0;             // buffer holding tile t
  int pc = 2;             // buffer holding tile t-1 (dummy at t=0)

  for (int t = 0; t < 32; t++){
    __syncthreads();                       // tile t staged (vmcnt drained); body(t-1) reads done
    int sc = (qc + 1 == 3) ? 0 : qc + 1;   // staging slot for t+1 (held t-2, now free)
    if (t < 31) ASTAGE(t + 1, sc);
    u64 wnext = (t < 31) ? wp[t + 1] : 0;

    // --- MFMA cluster: QK(t) then PV(t-1) (independent chains) ---
    f32x4 sa[4] = {};
    __builtin_amdgcn_s_setprio(1);
    #pragma unroll
    for (int nf = 0; nf < 4; nf++){
      #pragma unroll
      for (int ks = 0; ks < 2; ks++){
        bf16x8 kf = *(const bf16x8*)&Ks[qc][kaddr[nf][ks]];
        sa[nf] = __builtin_amdgcn_mfma_f32_16x16x32_bf16(kf, qf[ks], sa[nf], 0, 0, 0);
      }
    }
    if (t > 0){
      #pragma unroll
      for (int df = 0; df < 4; df++){
        #pragma unroll
        for (int c = 0; c < 2; c++){
          bf16x8 vf = *(const bf16x8*)&Vs[pc][vaddr[df][c]];
          o[df] = __builtin_amdgcn_mfma_f32_16x16x32_bf16(pa[c], vf, o[df], 0, 0, 0);
        }
      }
      osum = __builtin_amdgcn_mfma_f32_16x16x32_bf16(pa[0], onesb, osum, 0, 0, 0);
      osum = __builtin_amdgcn_mfma_f32_16x16x32_bf16(pa[1], onesb, osum, 0, 0, 0);
    }
    __builtin_amdgcn_s_setprio(0);

    // --- softmax(t): exp then sign-shift AND mask (VALU; overlaps PV above) ---
    uint32_t s0 = ((uint32_t)w) >> g4;
    uint32_t s1 = ((uint32_t)(w >> 32)) >> g4;
    float p[4][4];
    #pragma unroll
    for (int nf = 0; nf < 4; nf++){
      uint32_t ws = (nf < 2) ? s0 : s1;
      const int sh = (nf & 1) * 16;
      #pragma unroll
      for (int r = 0; r < 4; r++){
        int m = ((int)(ws << (31 - sh - r))) >> 31;   // all-ones iff mask bit set
        union { float f; int i; } u;
        u.f = __builtin_amdgcn_exp2f(sa[nf][r]);      // |sa| < ~40: exp2 safe
        u.i &= m;                                     // masked -> +0.0 exactly
        p[nf][r] = u.f;
      }
    }

    // --- pack(t) -> per-wave LDS bounce -> pa (for PV at body t+1) ---
    #pragma unroll
    for (int nf = 0; nf < 4; nf++){
      __hip_bfloat162 lo, hi;
      lo.x = __float2bfloat16(p[nf][0]); lo.y = __float2bfloat16(p[nf][1]);
      hi.x = __float2bfloat16(p[nf][2]); hi.y = __float2bfloat16(p[nf][3]);
      uint2 pk; pk.x = *(uint32_t*)&lo; pk.y = *(uint32_t*)&hi;
      *(uint2*)((char*)pb + pwb[nf]) = pk;
    }
    asm volatile("s_waitcnt lgkmcnt(0)" ::: "memory");
    #pragma unroll
    for (int c = 0; c < 2; c++)
      pa[c] = *(const bf16x8*)((const char*)pb + prb[c]);

    w = wnext;
    pc = qc; qc = sc;
  }

  // epilogue: PV(31) (pc holds tile 31's buffer after final rotate)
  __builtin_amdgcn_s_setprio(1);
  #pragma unroll
  for (int df = 0; df < 4; df++){
    #pragma unroll
    for (int c = 0; c < 2; c++){
      bf16x8 vf = *(const bf16x8*)&Vs[pc][vaddr[df][c]];
      o[df] = __builtin_amdgcn_mfma_f32_16x16x32_bf16(pa[c], vf, o[df], 0, 0, 0);
    }
  }
  osum = __builtin_amdgcn_mfma_f32_16x16x32_bf16(pa[0], onesb, osum, 0, 0, 0);
  osum = __builtin_amdgcn_mfma_f32_16x16x32_bf16(pa[1], onesb, osum, 0, 0, 0);
  __builtin_amdgcn_s_setprio(0);

  float li[4];
  #pragma unroll
  for (int r = 0; r < 4; r++) li[r] = 1.0f / osum[r];
  #pragma unroll
  for (int df = 0; df < 4; df++){
    #pragma unroll
    for (int r = 0; r < 4; r++){
      int s = q0 + wave*16 + g4 + r;
      int d = h*64 + df*16 + l15;
      AO[((size_t)b*2048 + s)*1024 + d] = f2bf(o[df][r] * li[r]);
    }
  }
}

// ---------------- launch ---------------------------------------------------------
extern "C" void kernel_launch(void* const* d_in, const int* in_sizes, int n_in,
                              void* d_out, int out_size, void* d_ws, size_t ws_size,
                              hipStream_t stream){
  const float* q   = (const float*)d_in[0];
  const float* k   = (const float*)d_in[1];
  const float* v   = (const float*)d_in[2];
  const int*   msk = (const int*)  d_in[3];
  const float* wq  = (const float*)d_in[4];
  const float* wk  = (const float*)d_in[5];
  const float* wv  = (const float*)d_in[6];
  const float* wo  = (const float*)d_in[7];
  const float* bo  = (const float*)d_in[8];

  char* ws = (char*)d_ws;
  ushort_t* conv = (ushort_t*)ws;                 // 33.5 MB of bf16 conversions
  ushort_t* qb  = conv;
  ushort_t* kb  = conv + 4194304;
  ushort_t* vb  = conv + 8388608;
  ushort_t* wqb = conv + 12582912;
  ushort_t* wkb = conv + 13631488;
  ushort_t* wvb = conv + 14680064;
  ushort_t* wob = conv + 15728640;
  u64*      mbits = (u64*)(ws + 33554432);        // 1 MB
  ushort_t* Qh  = (ushort_t*)(ws + 34603008);     // 8 MB
  ushort_t* Kh  = (ushort_t*)(ws + 42991616);     // 8 MB
  // Vt lives in d_out (scratch until gemm_out); must not alias gemm_qkv inputs.
  ushort_t* Vt  = (ushort_t*)d_out;
  ushort_t* AO  = qb;   // qb only read by gemm_qkv z=0 (earlier launch)

  prep_all<<<16384, 256, 0, stream>>>((const float4*)q, (const float4*)k,
      (const float4*)v, (const float4*)wq, (const float4*)wk, (const float4*)wv,
      (const float4*)wo, conv);

  const float qscale = 0.125f * LOG2E;   // fold score scale + log2(e) into Q
  gemm_qkv<<<dim3(32, 8, 4), 256, 0, stream>>>(qb, kb, vb, wqb, wkb, wvb,
                                               Qh, Kh, Vt, qscale,
                                               (const int4*)msk, mbits);

  attn_fused<<<512, 512, 0, stream>>>(Qh, Kh, Vt, mbits, AO);

  gemm_out<<<dim3(32, 8), 512, 0, stream>>>(AO, wob, (float*)d_out, bo);
}

// Round 18
// 128.060 us; speedup vs baseline: 1.0110x; 1.0110x over previous
//
#include <hip/hip_runtime.h>
#include <hip/hip_bf16.h>
#include <stdint.h>

typedef __attribute__((ext_vector_type(4))) float f32x4;
typedef __attribute__((ext_vector_type(8))) short bf16x8;
typedef __attribute__((ext_vector_type(4))) unsigned short us4;
typedef unsigned short ushort_t;
typedef unsigned long long u64;

#define LOG2E 1.44269504088896340f
#define NEGB  -1.0e9f

__device__ __forceinline__ unsigned short f2bf(float x){
  union { float f; uint32_t u; } v; v.f = x;
  uint32_t u = v.u + 0x7fffu + ((v.u >> 16) & 1u);
  return (unsigned short)(u >> 16);
}

__device__ __forceinline__ void gld16(const void* g, void* l){
  __builtin_amdgcn_global_load_lds(
      (const __attribute__((address_space(1))) unsigned int*)g,
      (__attribute__((address_space(3))) unsigned int*)l, 16, 0, 0);
}

// ---------------- prep: fp32 -> bf16 (q,k,v,Wq,Wk,Wv,Wo) -------------------------
__global__ void prep_all(const float4* __restrict__ q, const float4* __restrict__ k,
                         const float4* __restrict__ v, const float4* __restrict__ wq,
                         const float4* __restrict__ wk, const float4* __restrict__ wv,
                         const float4* __restrict__ wo, ushort_t* __restrict__ dst){
  int i = blockIdx.x * 256 + threadIdx.x;   // 0 .. 4194303 (float4 units)
  const float4* src; int base;
  if      (i < 1048576){ src = q;  base = 0; }
  else if (i < 2097152){ src = k;  base = 1048576; }
  else if (i < 3145728){ src = v;  base = 2097152; }
  else if (i < 3407872){ src = wq; base = 3145728; }
  else if (i < 3670016){ src = wk; base = 3407872; }
  else if (i < 3932160){ src = wv; base = 3670016; }
  else                 { src = wo; base = 3932160; }
  float4 f = src[i - base];
  us4 o; o.x = f2bf(f.x); o.y = f2bf(f.y); o.z = f2bf(f.z); o.w = f2bf(f.w);
  ((us4*)dst)[i] = o;
}

// ---------------- fused QKV projection GEMM (z selects q/k/v; z==3 packs mask) ---
// Vt must NOT alias anything read by z=0/1/2 blocks (intra-launch race, R5 bug):
// it lives in d_out, which is scratch until gemm_out.
__global__ void gemm_qkv(const ushort_t* __restrict__ qb, const ushort_t* __restrict__ kb,
                         const ushort_t* __restrict__ vb, const ushort_t* __restrict__ wqb,
                         const ushort_t* __restrict__ wkb, const ushort_t* __restrict__ wvb,
                         ushort_t* __restrict__ Qh, ushort_t* __restrict__ Kh,
                         ushort_t* __restrict__ Vt, float qscale,
                         const int4* __restrict__ mask, u64* __restrict__ mb){
  __shared__ ushort_t smem[16384];   // As[2][4096] | Bs[2][4096]; reused as T post-loop
#define AsQ(c) (smem + (c)*4096)
#define BsQ(c) (smem + 8192 + (c)*4096)
  const int z = blockIdx.z;
  if (z == 3){
    // mask pack: 256 blocks * 256 thr * 2 words = 131072 u64 words
    int bid2 = blockIdx.x + (blockIdx.y << 5);
    #pragma unroll
    for (int rep = 0; rep < 2; rep++){
      int w = bid2 * 512 + rep * 256 + threadIdx.x;
      const int4* p = mask + (size_t)w * 16;
      u64 bits = 0;
      #pragma unroll
      for (int j = 0; j < 16; j++){
        int4 m = p[j];
        bits |= (u64)(m.x != 0) << (j*4);
        bits |= (u64)(m.y != 0) << (j*4+1);
        bits |= (u64)(m.z != 0) << (j*4+2);
        bits |= (u64)(m.w != 0) << (j*4+3);
      }
      mb[w] = bits;
    }
    return;
  }
  const ushort_t* A = (z == 0) ? qb  : (z == 1) ? kb  : vb;
  const ushort_t* B = (z == 0) ? wqb : (z == 1) ? wkb : wvb;
  ushort_t*       C = (z == 0) ? Qh  : (z == 1) ? Kh  : Vt;
  const float scale = (z == 0) ? qscale : 1.0f;

  const int tid = threadIdx.x, wave = tid >> 6, lane = tid & 63;
  const int l15 = lane & 15;
  const int m0 = blockIdx.x * 128, n0 = blockIdx.y * 128;
  const int wr = wave >> 1, wc = wave & 1;
  f32x4 acc[4][4] = {};

  const ushort_t* Ag = A + (size_t)(m0 + wave*16 + (lane>>2)) * 1024 + (lane&3)*8;
  const ushort_t* Bg = B + (size_t)(n0 + wave*16 + (lane>>2)) * 1024 + (lane&3)*8;

#define GSTAGE(k0, c) do { \
    gld16(Ag + (k0),         AsQ(c) + wave*512); \
    gld16(Ag + 65536 + (k0), AsQ(c) + (4+wave)*512); \
    gld16(Bg + (k0),         BsQ(c) + wave*512); \
    gld16(Bg + 65536 + (k0), BsQ(c) + (4+wave)*512); } while(0)

  GSTAGE(0, 0);
  int cur = 0;
  for (int k0 = 0; k0 < 1024; k0 += 32){
    __syncthreads();                     // buf[cur] staged (vmcnt drained); prev reads done
    if (k0 < 992) GSTAGE(k0 + 32, cur ^ 1);
    bf16x8 a[4], b[4];
    #pragma unroll
    for (int i = 0; i < 4; i++){
      a[i] = *(const bf16x8*)&AsQ(cur)[(wr*64 + i*16 + l15)*32 + (lane>>4)*8];
      b[i] = *(const bf16x8*)&BsQ(cur)[(wc*64 + i*16 + l15)*32 + (lane>>4)*8];
    }
    __builtin_amdgcn_s_setprio(1);
    #pragma unroll
    for (int i = 0; i < 4; i++)
      #pragma unroll
      for (int j = 0; j < 4; j++)
        acc[i][j] = __builtin_amdgcn_mfma_f32_16x16x32_bf16(a[i], b[j], acc[i][j], 0, 0, 0);
    __builtin_amdgcn_s_setprio(0);
    cur ^= 1;
  }

  if (z < 2){
    #pragma unroll
    for (int i = 0; i < 4; i++){
      #pragma unroll
      for (int j = 0; j < 4; j++){
        #pragma unroll
        for (int r = 0; r < 4; r++){
          int row = m0 + wr*64 + i*16 + (lane>>4)*4 + r;
          int col = n0 + wc*64 + j*16 + l15;
          int bb = row >> 11, s = row & 2047, h = col >> 6, d = col & 63;
          C[((size_t)(bb*16 + h)*2048 + s)*64 + d] = f2bf(acc[i][j][r] * scale);
        }
      }
    }
  } else {
    // transpose epilogue: two 64-col halves through LDS T[64][136]
    ushort_t* T = smem;
    #pragma unroll
    for (int hh = 0; hh < 2; hh++){
      __syncthreads();
      if (wc == hh){
        #pragma unroll
        for (int i = 0; i < 4; i++){
          #pragma unroll
          for (int j = 0; j < 4; j++){
            int n = j*16 + l15;
            int mb2 = wr*64 + i*16 + (lane>>4)*4;
            us4 pk;
            pk.x = f2bf(acc[i][j][0]); pk.y = f2bf(acc[i][j][1]);
            pk.z = f2bf(acc[i][j][2]); pk.w = f2bf(acc[i][j][3]);
            *(us4*)&T[n*136 + mb2] = pk;
          }
        }
      }
      __syncthreads();
      #pragma unroll
      for (int cc = 0; cc < 4; cc++){
        int chunk = cc*256 + tid;
        int n = chunk >> 4, mc = chunk & 15;
        uint4 val = *(uint4*)&T[n*136 + mc*8];
        int col = n0 + hh*64 + n;
        int hcol = col >> 6, d = col & 63;
        int row = m0 + mc*8;
        int bb2 = row >> 11, s = row & 2047;
        *(uint4*)&C[((size_t)(bb2*16 + hcol)*64 + d)*2048 + s] = val;
      }
    }
  }
}

// ---------------- output GEMM: fp32 [M,N] = A[M,K] * W[N,K]^T + bias -------------
// 512 threads / 8 waves (4 m-bands x 2 n-bands, wave tile 32x64).
__global__ __launch_bounds__(512)
void gemm_out(const ushort_t* __restrict__ A, const ushort_t* __restrict__ B,
              float* __restrict__ C, const float* __restrict__ bias){
  __shared__ ushort_t As[2][4096];
  __shared__ ushort_t Bs[2][4096];
  const int tid = threadIdx.x, wave = tid >> 6, lane = tid & 63;
  const int l15 = lane & 15;
  const int m0 = blockIdx.x * 128, n0 = blockIdx.y * 128;
  const int wr = wave >> 1, wc = wave & 1;
  f32x4 acc[2][4] = {};

  const ushort_t* Ag = A + (size_t)(m0 + wave*16 + (lane>>2)) * 1024 + (lane&3)*8;
  const ushort_t* Bg = B + (size_t)(n0 + wave*16 + (lane>>2)) * 1024 + (lane&3)*8;

#define GSTAGE2(k0, c) do { \
    gld16(Ag + (k0), &As[c][wave*512]); \
    gld16(Bg + (k0), &Bs[c][wave*512]); } while(0)

  GSTAGE2(0, 0);
  int cur = 0;
  for (int k0 = 0; k0 < 1024; k0 += 32){
    __syncthreads();
    if (k0 < 992) GSTAGE2(k0 + 32, cur ^ 1);
    bf16x8 a[2], b[4];
    #pragma unroll
    for (int i = 0; i < 2; i++)
      a[i] = *(const bf16x8*)&As[cur][(wr*32 + i*16 + l15)*32 + (lane>>4)*8];
    #pragma unroll
    for (int j = 0; j < 4; j++)
      b[j] = *(const bf16x8*)&Bs[cur][(wc*64 + j*16 + l15)*32 + (lane>>4)*8];
    __builtin_amdgcn_s_setprio(1);
    #pragma unroll
    for (int i = 0; i < 2; i++)
      #pragma unroll
      for (int j = 0; j < 4; j++)
        acc[i][j] = __builtin_amdgcn_mfma_f32_16x16x32_bf16(a[i], b[j], acc[i][j], 0, 0, 0);
    __builtin_amdgcn_s_setprio(0);
    cur ^= 1;
  }

  #pragma unroll
  for (int i = 0; i < 2; i++){
    #pragma unroll
    for (int j = 0; j < 4; j++){
      #pragma unroll
      for (int r = 0; r < 4; r++){
        int row = m0 + wr*32 + i*16 + (lane>>4)*4 + r;
        int col = n0 + wc*64 + j*16 + l15;
        C[(size_t)row * 1024 + col] = acc[i][j][r] + bias[col];
      }
    }
  }
}

// ---------------- fused flash attention (triple-buffer, deferred PV) -------------
// grid: 512 = B(2)*H(16)*(S/128).  8 waves, each owns 16 q-rows (q-tile 128).
// Software pipeline across kv-tiles: body(t) = QK(t) + PV(t-1) + softmax(t) +
// pack(t).  Triple buffer: live tiles {t-1 (PV), t (QK), t+1 (stage)}.
__global__ void attn_fused(const ushort_t* __restrict__ Qh, const ushort_t* __restrict__ Kh,
                           const ushort_t* __restrict__ Vt, const u64* __restrict__ MB,
                           ushort_t* __restrict__ AO){
  __shared__ ushort_t Ks[3][4096];  // 64 kv x 64 d, XOR-swizzled rows (128B)
  __shared__ ushort_t Vs[3][4096];  // 64 d  x 64 kv, XOR-swizzled
  __shared__ ushort_t Pb[8][1024];  // per-wave 16 q x 64 kv, XOR-swizzled

  const int tid = threadIdx.x, wave = tid >> 6, lane = tid & 63;
  const int g = lane >> 4, l15 = lane & 15;
  const int wg = ((blockIdx.x & 7) << 6) | (blockIdx.x >> 3);   // XCD swizzle (512=8*64)
  const int qt = wg & 15, h = (wg >> 4) & 15, b = wg >> 8;
  const int q0 = qt * 128;

  const ushort_t* Qb = Qh + ((size_t)(b*16 + h)*2048 + q0) * 64;
  const ushort_t* Kb = Kh + ((size_t)(b*16 + h)*2048) * 64;
  const ushort_t* Vb = Vt + ((size_t)(b*16 + h)*64) * 2048;
  const u64* wp = MB + ((size_t)b*2048 + q0 + wave*16 + l15) * 32;

  bf16x8 qf[2];
  #pragma unroll
  for (int ks = 0; ks < 2; ks++)
    qf[ks] = *(const bf16x8*)&Qb[(wave*16 + l15)*64 + ks*32 + g*8];

  bf16x8 onesb;
  #pragma unroll
  for (int j = 0; j < 8; j++) onesb[j] = (short)0x3F80;

  f32x4 o[4] = {};
  f32x4 osum = {};

  const int srow = lane >> 3;
  const int scol = ((lane & 7) * 16) ^ (srow << 4);
  const ushort_t* Kg = Kb + (size_t)(wave*8 + srow)*64   + (scol >> 1);
  const ushort_t* Vg = Vb + (size_t)(wave*8 + srow)*2048 + (scol >> 1);
  ushort_t* pb = &Pb[wave][0];
  const int xv = (l15 & 7) << 4;
  const int g4 = g * 4;

  // loop-invariant swizzled LDS offsets (ushort / byte units)
  int kaddr[4][2], vaddr[4][2], pwb[4], prb[2];
  #pragma unroll
  for (int nf = 0; nf < 4; nf++){
    int row = nf*16 + l15;
    #pragma unroll
    for (int ks = 0; ks < 2; ks++){
      int cb = (ks*64 + g*16) ^ ((row & 7) << 4);
      kaddr[nf][ks] = row*64 + (cb >> 1);
    }
  }
  #pragma unroll
  for (int df = 0; df < 4; df++){
    int vrow = df*16 + l15;
    #pragma unroll
    for (int c = 0; c < 2; c++){
      int cb = (c*64 + g*16) ^ ((vrow & 7) << 4);
      vaddr[df][c] = vrow*64 + (cb >> 1);
    }
  }
  #pragma unroll
  for (int nf = 0; nf < 4; nf++)
    pwb[nf] = l15*128 + ((nf*32 + g*8) ^ xv);
  #pragma unroll
  for (int c = 0; c < 2; c++)
    prb[c] = l15*128 + ((c*64 + g*16) ^ xv);

#define ASTAGE(t, c) do { \
    gld16(Kg + (size_t)(t)*4096, &Ks[c][wave*512]); \
    gld16(Vg + (t)*64,           &Vs[c][wave*512]); } while(0)

  ASTAGE(0, 0);
  u64 w = wp[0];
  bf16x8 pa[2];           // P fragment of tile t-1 (valid from t>=1)
  int qc = 0;             // buffer holding tile t
  int pc = 2;             // buffer holding tile t-1 (dummy at t=0)

  for (int t = 0; t < 32; t++){
    __syncthreads();                       // tile t staged (vmcnt drained); body(t-1) reads done
    int sc = (qc + 1 == 3) ? 0 : qc + 1;   // staging slot for t+1 (held t-2, now free)
    if (t < 31) ASTAGE(t + 1, sc);
    u64 wnext = (t < 31) ? wp[t + 1] : 0;

    // --- MFMA cluster: QK(t) then PV(t-1) (independent chains) ---
    f32x4 sa[4] = {};
    __builtin_amdgcn_s_setprio(1);
    #pragma unroll
    for (int nf = 0; nf < 4; nf++){
      #pragma unroll
      for (int ks = 0; ks < 2; ks++){
        bf16x8 kf = *(const bf16x8*)&Ks[qc][kaddr[nf][ks]];
        sa[nf] = __builtin_amdgcn_mfma_f32_16x16x32_bf16(kf, qf[ks], sa[nf], 0, 0, 0);
      }
    }
    if (t > 0){
      #pragma unroll
      for (int df = 0; df < 4; df++){
        #pragma unroll
        for (int c = 0; c < 2; c++){
          bf16x8 vf = *(const bf16x8*)&Vs[pc][vaddr[df][c]];
          o[df] = __builtin_amdgcn_mfma_f32_16x16x32_bf16(pa[c], vf, o[df], 0, 0, 0);
        }
      }
      osum = __builtin_amdgcn_mfma_f32_16x16x32_bf16(pa[0], onesb, osum, 0, 0, 0);
      osum = __builtin_amdgcn_mfma_f32_16x16x32_bf16(pa[1], onesb, osum, 0, 0, 0);
    }
    __builtin_amdgcn_s_setprio(0);

    // --- softmax(t): mask + exp (VALU; overlaps the PV MFMAs above) ---
    uint32_t s0 = ((uint32_t)w) >> g4;
    uint32_t s1 = ((uint32_t)(w >> 32)) >> g4;
    float p[4][4];
    #pragma unroll
    for (int nf = 0; nf < 4; nf++){
      uint32_t ws = (nf < 2) ? s0 : s1;
      const int sh = (nf & 1) * 16;
      #pragma unroll
      for (int r = 0; r < 4; r++){
        float s = ((ws >> (sh + r)) & 1u) ? sa[nf][r] : NEGB;
        p[nf][r] = __builtin_amdgcn_exp2f(s);   // masked -> exp2(-1e9) == +0.0
      }
    }

    // --- pack(t) -> per-wave LDS bounce -> pa (for PV at body t+1) ---
    #pragma unroll
    for (int nf = 0; nf < 4; nf++){
      __hip_bfloat162 lo, hi;
      lo.x = __float2bfloat16(p[nf][0]); lo.y = __float2bfloat16(p[nf][1]);
      hi.x = __float2bfloat16(p[nf][2]); hi.y = __float2bfloat16(p[nf][3]);
      uint2 pk; pk.x = *(uint32_t*)&lo; pk.y = *(uint32_t*)&hi;
      *(uint2*)((char*)pb + pwb[nf]) = pk;
    }
    asm volatile("s_waitcnt lgkmcnt(0)" ::: "memory");
    #pragma unroll
    for (int c = 0; c < 2; c++)
      pa[c] = *(const bf16x8*)((const char*)pb + prb[c]);

    w = wnext;
    pc = qc; qc = sc;
  }

  // epilogue: PV(31) (pc holds tile 31's buffer after final rotate)
  __builtin_amdgcn_s_setprio(1);
  #pragma unroll
  for (int df = 0; df < 4; df++){
    #pragma unroll
    for (int c = 0; c < 2; c++){
      bf16x8 vf = *(const bf16x8*)&Vs[pc][vaddr[df][c]];
      o[df] = __builtin_amdgcn_mfma_f32_16x16x32_bf16(pa[c], vf, o[df], 0, 0, 0);
    }
  }
  osum = __builtin_amdgcn_mfma_f32_16x16x32_bf16(pa[0], onesb, osum, 0, 0, 0);
  osum = __builtin_amdgcn_mfma_f32_16x16x32_bf16(pa[1], onesb, osum, 0, 0, 0);
  __builtin_amdgcn_s_setprio(0);

  float li[4];
  #pragma unroll
  for (int r = 0; r < 4; r++) li[r] = 1.0f / osum[r];
  #pragma unroll
  for (int df = 0; df < 4; df++){
    #pragma unroll
    for (int r = 0; r < 4; r++){
      int s = q0 + wave*16 + g4 + r;
      int d = h*64 + df*16 + l15;
      AO[((size_t)b*2048 + s)*1024 + d] = f2bf(o[df][r] * li[r]);
    }
  }
}

// ---------------- launch ---------------------------------------------------------
extern "C" void kernel_launch(void* const* d_in, const int* in_sizes, int n_in,
                              void* d_out, int out_size, void* d_ws, size_t ws_size,
                              hipStream_t stream){
  const float* q   = (const float*)d_in[0];
  const float* k   = (const float*)d_in[1];
  const float* v   = (const float*)d_in[2];
  const int*   msk = (const int*)  d_in[3];
  const float* wq  = (const float*)d_in[4];
  const float* wk  = (const float*)d_in[5];
  const float* wv  = (const float*)d_in[6];
  const float* wo  = (const float*)d_in[7];
  const float* bo  = (const float*)d_in[8];

  char* ws = (char*)d_ws;
  ushort_t* conv = (ushort_t*)ws;                 // 33.5 MB of bf16 conversions
  ushort_t* qb  = conv;
  ushort_t* kb  = conv + 4194304;
  ushort_t* vb  = conv + 8388608;
  ushort_t* wqb = conv + 12582912;
  ushort_t* wkb = conv + 13631488;
  ushort_t* wvb = conv + 14680064;
  ushort_t* wob = conv + 15728640;
  u64*      mbits = (u64*)(ws + 33554432);        // 1 MB
  ushort_t* Qh  = (ushort_t*)(ws + 34603008);     // 8 MB
  ushort_t* Kh  = (ushort_t*)(ws + 42991616);     // 8 MB
  // Vt lives in d_out (scratch until gemm_out); must not alias gemm_qkv inputs.
  ushort_t* Vt  = (ushort_t*)d_out;
  ushort_t* AO  = qb;   // qb only read by gemm_qkv z=0 (earlier launch)

  prep_all<<<16384, 256, 0, stream>>>((const float4*)q, (const float4*)k,
      (const float4*)v, (const float4*)wq, (const float4*)wk, (const float4*)wv,
      (const float4*)wo, conv);

  const float qscale = 0.125f * LOG2E;   // fold score scale + log2(e) into Q
  gemm_qkv<<<dim3(32, 8, 4), 256, 0, stream>>>(qb, kb, vb, wqb, wkb, wvb,
                                               Qh, Kh, Vt, qscale,
                                               (const int4*)msk, mbits);

  attn_fused<<<512, 512, 0, stream>>>(Qh, Kh, Vt, mbits, AO);

  gemm_out<<<dim3(32, 8), 512, 0, stream>>>(AO, wob, (float*)d_out, bo);
}

// Round 19
// 126.611 us; speedup vs baseline: 1.0225x; 1.0114x over previous
//
#include <hip/hip_runtime.h>
#include <hip/hip_bf16.h>
#include <stdint.h>

typedef __attribute__((ext_vector_type(4))) float f32x4;
typedef __attribute__((ext_vector_type(8))) short bf16x8;
typedef __attribute__((ext_vector_type(4))) unsigned short us4;
typedef unsigned short ushort_t;
typedef unsigned long long u64;

#define LOG2E 1.44269504088896340f
#define NEGB  -1.0e9f

__device__ __forceinline__ unsigned short f2bf(float x){
  union { float f; uint32_t u; } v; v.f = x;
  uint32_t u = v.u + 0x7fffu + ((v.u >> 16) & 1u);
  return (unsigned short)(u >> 16);
}

__device__ __forceinline__ void gld16(const void* g, void* l){
  __builtin_amdgcn_global_load_lds(
      (const __attribute__((address_space(1))) unsigned int*)g,
      (__attribute__((address_space(3))) unsigned int*)l, 16, 0, 0);
}

// ---------------- prep: fp32 -> bf16 (q,k,v,Wq,Wk,Wv,Wo) -------------------------
__global__ void prep_all(const float4* __restrict__ q, const float4* __restrict__ k,
                         const float4* __restrict__ v, const float4* __restrict__ wq,
                         const float4* __restrict__ wk, const float4* __restrict__ wv,
                         const float4* __restrict__ wo, ushort_t* __restrict__ dst){
  int i = blockIdx.x * 256 + threadIdx.x;   // 0 .. 4194303 (float4 units)
  const float4* src; int base;
  if      (i < 1048576){ src = q;  base = 0; }
  else if (i < 2097152){ src = k;  base = 1048576; }
  else if (i < 3145728){ src = v;  base = 2097152; }
  else if (i < 3407872){ src = wq; base = 3145728; }
  else if (i < 3670016){ src = wk; base = 3407872; }
  else if (i < 3932160){ src = wv; base = 3670016; }
  else                 { src = wo; base = 3932160; }
  float4 f = src[i - base];
  us4 o; o.x = f2bf(f.x); o.y = f2bf(f.y); o.z = f2bf(f.z); o.w = f2bf(f.w);
  ((us4*)dst)[i] = o;
}

// ---------------- fused QKV projection GEMM (z selects q/k/v; z==3 packs mask) ---
// Vt must NOT alias anything read by z=0/1/2 blocks (intra-launch race, R5 bug):
// it lives in d_out, which is scratch until gemm_out.
__global__ void gemm_qkv(const ushort_t* __restrict__ qb, const ushort_t* __restrict__ kb,
                         const ushort_t* __restrict__ vb, const ushort_t* __restrict__ wqb,
                         const ushort_t* __restrict__ wkb, const ushort_t* __restrict__ wvb,
                         ushort_t* __restrict__ Qh, ushort_t* __restrict__ Kh,
                         ushort_t* __restrict__ Vt, float qscale,
                         const int4* __restrict__ mask, u64* __restrict__ mb){
  __shared__ ushort_t smem[16384];   // As[2][4096] | Bs[2][4096]; reused as T post-loop
#define AsQ(c) (smem + (c)*4096)
#define BsQ(c) (smem + 8192 + (c)*4096)
  const int z = blockIdx.z;
  if (z == 3){
    // mask pack: 256 blocks * 256 thr * 2 words = 131072 u64 words
    int bid2 = blockIdx.x + (blockIdx.y << 5);
    #pragma unroll
    for (int rep = 0; rep < 2; rep++){
      int w = bid2 * 512 + rep * 256 + threadIdx.x;
      const int4* p = mask + (size_t)w * 16;
      u64 bits = 0;
      #pragma unroll
      for (int j = 0; j < 16; j++){
        int4 m = p[j];
        bits |= (u64)(m.x != 0) << (j*4);
        bits |= (u64)(m.y != 0) << (j*4+1);
        bits |= (u64)(m.z != 0) << (j*4+2);
        bits |= (u64)(m.w != 0) << (j*4+3);
      }
      mb[w] = bits;
    }
    return;
  }
  const ushort_t* A = (z == 0) ? qb  : (z == 1) ? kb  : vb;
  const ushort_t* B = (z == 0) ? wqb : (z == 1) ? wkb : wvb;
  ushort_t*       C = (z == 0) ? Qh  : (z == 1) ? Kh  : Vt;
  const float scale = (z == 0) ? qscale : 1.0f;

  const int tid = threadIdx.x, wave = tid >> 6, lane = tid & 63;
  const int l15 = lane & 15;
  const int m0 = blockIdx.x * 128, n0 = blockIdx.y * 128;
  const int wr = wave >> 1, wc = wave & 1;
  f32x4 acc[4][4] = {};

  const ushort_t* Ag = A + (size_t)(m0 + wave*16 + (lane>>2)) * 1024 + (lane&3)*8;
  const ushort_t* Bg = B + (size_t)(n0 + wave*16 + (lane>>2)) * 1024 + (lane&3)*8;

#define GSTAGE(k0, c) do { \
    gld16(Ag + (k0),         AsQ(c) + wave*512); \
    gld16(Ag + 65536 + (k0), AsQ(c) + (4+wave)*512); \
    gld16(Bg + (k0),         BsQ(c) + wave*512); \
    gld16(Bg + 65536 + (k0), BsQ(c) + (4+wave)*512); } while(0)

  GSTAGE(0, 0);
  int cur = 0;
  for (int k0 = 0; k0 < 1024; k0 += 32){
    __syncthreads();                     // buf[cur] staged (vmcnt drained); prev reads done
    if (k0 < 992) GSTAGE(k0 + 32, cur ^ 1);
    bf16x8 a[4], b[4];
    #pragma unroll
    for (int i = 0; i < 4; i++){
      a[i] = *(const bf16x8*)&AsQ(cur)[(wr*64 + i*16 + l15)*32 + (lane>>4)*8];
      b[i] = *(const bf16x8*)&BsQ(cur)[(wc*64 + i*16 + l15)*32 + (lane>>4)*8];
    }
    __builtin_amdgcn_s_setprio(1);
    #pragma unroll
    for (int i = 0; i < 4; i++)
      #pragma unroll
      for (int j = 0; j < 4; j++)
        acc[i][j] = __builtin_amdgcn_mfma_f32_16x16x32_bf16(a[i], b[j], acc[i][j], 0, 0, 0);
    __builtin_amdgcn_s_setprio(0);
    cur ^= 1;
  }

  if (z < 2){
    #pragma unroll
    for (int i = 0; i < 4; i++){
      #pragma unroll
      for (int j = 0; j < 4; j++){
        #pragma unroll
        for (int r = 0; r < 4; r++){
          int row = m0 + wr*64 + i*16 + (lane>>4)*4 + r;
          int col = n0 + wc*64 + j*16 + l15;
          int bb = row >> 11, s = row & 2047, h = col >> 6, d = col & 63;
          C[((size_t)(bb*16 + h)*2048 + s)*64 + d] = f2bf(acc[i][j][r] * scale);
        }
      }
    }
  } else {
    // transpose epilogue: two 64-col halves through LDS T[64][136]
    ushort_t* T = smem;
    #pragma unroll
    for (int hh = 0; hh < 2; hh++){
      __syncthreads();
      if (wc == hh){
        #pragma unroll
        for (int i = 0; i < 4; i++){
          #pragma unroll
          for (int j = 0; j < 4; j++){
            int n = j*16 + l15;
            int mb2 = wr*64 + i*16 + (lane>>4)*4;
            us4 pk;
            pk.x = f2bf(acc[i][j][0]); pk.y = f2bf(acc[i][j][1]);
            pk.z = f2bf(acc[i][j][2]); pk.w = f2bf(acc[i][j][3]);
            *(us4*)&T[n*136 + mb2] = pk;
          }
        }
      }
      __syncthreads();
      #pragma unroll
      for (int cc = 0; cc < 4; cc++){
        int chunk = cc*256 + tid;
        int n = chunk >> 4, mc = chunk & 15;
        uint4 val = *(uint4*)&T[n*136 + mc*8];
        int col = n0 + hh*64 + n;
        int hcol = col >> 6, d = col & 63;
        int row = m0 + mc*8;
        int bb2 = row >> 11, s = row & 2047;
        *(uint4*)&C[((size_t)(bb2*16 + hcol)*64 + d)*2048 + s] = val;
      }
    }
  }
}

// ---------------- output GEMM: fp32 [M,N] = A[M,K] * W[N,K]^T + bias -------------
// 512 threads / 8 waves (4 m-bands x 2 n-bands, wave tile 32x64).
__global__ __launch_bounds__(512)
void gemm_out(const ushort_t* __restrict__ A, const ushort_t* __restrict__ B,
              float* __restrict__ C, const float* __restrict__ bias){
  __shared__ ushort_t As[2][4096];
  __shared__ ushort_t Bs[2][4096];
  const int tid = threadIdx.x, wave = tid >> 6, lane = tid & 63;
  const int l15 = lane & 15;
  const int m0 = blockIdx.x * 128, n0 = blockIdx.y * 128;
  const int wr = wave >> 1, wc = wave & 1;
  f32x4 acc[2][4] = {};

  const ushort_t* Ag = A + (size_t)(m0 + wave*16 + (lane>>2)) * 1024 + (lane&3)*8;
  const ushort_t* Bg = B + (size_t)(n0 + wave*16 + (lane>>2)) * 1024 + (lane&3)*8;

#define GSTAGE2(k0, c) do { \
    gld16(Ag + (k0), &As[c][wave*512]); \
    gld16(Bg + (k0), &Bs[c][wave*512]); } while(0)

  GSTAGE2(0, 0);
  int cur = 0;
  for (int k0 = 0; k0 < 1024; k0 += 32){
    __syncthreads();
    if (k0 < 992) GSTAGE2(k0 + 32, cur ^ 1);
    bf16x8 a[2], b[4];
    #pragma unroll
    for (int i = 0; i < 2; i++)
      a[i] = *(const bf16x8*)&As[cur][(wr*32 + i*16 + l15)*32 + (lane>>4)*8];
    #pragma unroll
    for (int j = 0; j < 4; j++)
      b[j] = *(const bf16x8*)&Bs[cur][(wc*64 + j*16 + l15)*32 + (lane>>4)*8];
    __builtin_amdgcn_s_setprio(1);
    #pragma unroll
    for (int i = 0; i < 2; i++)
      #pragma unroll
      for (int j = 0; j < 4; j++)
        acc[i][j] = __builtin_amdgcn_mfma_f32_16x16x32_bf16(a[i], b[j], acc[i][j], 0, 0, 0);
    __builtin_amdgcn_s_setprio(0);
    cur ^= 1;
  }

  #pragma unroll
  for (int i = 0; i < 2; i++){
    #pragma unroll
    for (int j = 0; j < 4; j++){
      #pragma unroll
      for (int r = 0; r < 4; r++){
        int row = m0 + wr*32 + i*16 + (lane>>4)*4 + r;
        int col = n0 + wc*64 + j*16 + l15;
        C[(size_t)row * 1024 + col] = acc[i][j][r] + bias[col];
      }
    }
  }
}

// ---------------- fused flash attention (triple-buffer, deferred PV, q-tile 256) -
// grid: 256 = B(2)*H(16)*(S/256).  16 waves / 1024 threads; wave owns 16 q-rows.
// Same pipelined body as the proven 8-wave version; waves 0-7 stage K, 8-15
// stage V (1 gld16/wave/tile).  K/V staged once per 256 q-rows (FETCH halves);
// grid 256 = exactly 1 block/CU (no scheduling rounds, no cross-block LDS
// interference).  Occupancy unchanged at 16 waves/CU.
__global__ __launch_bounds__(1024)
void attn_fused(const ushort_t* __restrict__ Qh, const ushort_t* __restrict__ Kh,
                const ushort_t* __restrict__ Vt, const u64* __restrict__ MB,
                ushort_t* __restrict__ AO){
  __shared__ ushort_t Ks[3][4096];  // 64 kv x 64 d, XOR-swizzled rows (128B)
  __shared__ ushort_t Vs[3][4096];  // 64 d  x 64 kv, XOR-swizzled
  __shared__ ushort_t Pb[16][1024]; // per-wave 16 q x 64 kv, XOR-swizzled

  const int tid = threadIdx.x, wave = tid >> 6, lane = tid & 63;
  const int g = lane >> 4, l15 = lane & 15;
  const int wg = ((blockIdx.x & 7) << 5) | (blockIdx.x >> 3);   // XCD swizzle (256=8*32)
  const int qt = wg & 7, h = (wg >> 3) & 15, b = wg >> 7;
  const int q0 = qt * 256;

  const ushort_t* Qb = Qh + ((size_t)(b*16 + h)*2048 + q0) * 64;
  const ushort_t* Kb = Kh + ((size_t)(b*16 + h)*2048) * 64;
  const ushort_t* Vb = Vt + ((size_t)(b*16 + h)*64) * 2048;
  const u64* wp = MB + ((size_t)b*2048 + q0 + wave*16 + l15) * 32;

  bf16x8 qf[2];
  #pragma unroll
  for (int ks = 0; ks < 2; ks++)
    qf[ks] = *(const bf16x8*)&Qb[(wave*16 + l15)*64 + ks*32 + g*8];

  bf16x8 onesb;
  #pragma unroll
  for (int j = 0; j < 8; j++) onesb[j] = (short)0x3F80;

  f32x4 o[4] = {};
  f32x4 osum = {};

  // staging: waves 0-7 stage K rows (w8*8..w8*8+7), waves 8-15 stage V rows
  const int w8 = wave & 7;
  const int srow = lane >> 3;
  const int scol = ((lane & 7) * 16) ^ (srow << 4);
  const ushort_t* Kg = Kb + (size_t)(w8*8 + srow)*64   + (scol >> 1);
  const ushort_t* Vg = Vb + (size_t)(w8*8 + srow)*2048 + (scol >> 1);
  ushort_t* pb = &Pb[wave][0];
  const int xv = (l15 & 7) << 4;
  const int g4 = g * 4;

  // loop-invariant swizzled LDS offsets (ushort / byte units)
  int kaddr[4][2], vaddr[4][2], pwb[4], prb[2];
  #pragma unroll
  for (int nf = 0; nf < 4; nf++){
    int row = nf*16 + l15;
    #pragma unroll
    for (int ks = 0; ks < 2; ks++){
      int cb = (ks*64 + g*16) ^ ((row & 7) << 4);
      kaddr[nf][ks] = row*64 + (cb >> 1);
    }
  }
  #pragma unroll
  for (int df = 0; df < 4; df++){
    int vrow = df*16 + l15;
    #pragma unroll
    for (int c = 0; c < 2; c++){
      int cb = (c*64 + g*16) ^ ((vrow & 7) << 4);
      vaddr[df][c] = vrow*64 + (cb >> 1);
    }
  }
  #pragma unroll
  for (int nf = 0; nf < 4; nf++)
    pwb[nf] = l15*128 + ((nf*32 + g*8) ^ xv);
  #pragma unroll
  for (int c = 0; c < 2; c++)
    prb[c] = l15*128 + ((c*64 + g*16) ^ xv);

#define ASTAGE(t, c) do { \
    if (wave < 8) gld16(Kg + (size_t)(t)*4096, &Ks[c][w8*512]); \
    else          gld16(Vg + (t)*64,           &Vs[c][w8*512]); } while(0)

  ASTAGE(0, 0);
  u64 w = wp[0];
  bf16x8 pa[2];           // P fragment of tile t-1 (valid from t>=1)
  int qc = 0;             // buffer holding tile t
  int pc = 2;             // buffer holding tile t-1 (dummy at t=0)

  for (int t = 0; t < 32; t++){
    __syncthreads();                       // tile t staged (vmcnt drained); body(t-1) reads done
    int sc = (qc + 1 == 3) ? 0 : qc + 1;   // staging slot for t+1 (held t-2, now free)
    if (t < 31) ASTAGE(t + 1, sc);
    u64 wnext = (t < 31) ? wp[t + 1] : 0;

    // --- MFMA cluster: QK(t) then PV(t-1) (independent chains) ---
    f32x4 sa[4] = {};
    __builtin_amdgcn_s_setprio(1);
    #pragma unroll
    for (int nf = 0; nf < 4; nf++){
      #pragma unroll
      for (int ks = 0; ks < 2; ks++){
        bf16x8 kf = *(const bf16x8*)&Ks[qc][kaddr[nf][ks]];
        sa[nf] = __builtin_amdgcn_mfma_f32_16x16x32_bf16(kf, qf[ks], sa[nf], 0, 0, 0);
      }
    }
    if (t > 0){
      #pragma unroll
      for (int df = 0; df < 4; df++){
        #pragma unroll
        for (int c = 0; c < 2; c++){
          bf16x8 vf = *(const bf16x8*)&Vs[pc][vaddr[df][c]];
          o[df] = __builtin_amdgcn_mfma_f32_16x16x32_bf16(pa[c], vf, o[df], 0, 0, 0);
        }
      }
      osum = __builtin_amdgcn_mfma_f32_16x16x32_bf16(pa[0], onesb, osum, 0, 0, 0);
      osum = __builtin_amdgcn_mfma_f32_16x16x32_bf16(pa[1], onesb, osum, 0, 0, 0);
    }
    __builtin_amdgcn_s_setprio(0);

    // --- softmax(t): mask + exp (VALU; overlaps the PV MFMAs above) ---
    uint32_t s0 = ((uint32_t)w) >> g4;
    uint32_t s1 = ((uint32_t)(w >> 32)) >> g4;
    float p[4][4];
    #pragma unroll
    for (int nf = 0; nf < 4; nf++){
      uint32_t ws = (nf < 2) ? s0 : s1;
      const int sh = (nf & 1) * 16;
      #pragma unroll
      for (int r = 0; r < 4; r++){
        float s = ((ws >> (sh + r)) & 1u) ? sa[nf][r] : NEGB;
        p[nf][r] = __builtin_amdgcn_exp2f(s);   // masked -> exp2(-1e9) == +0.0
      }
    }

    // --- pack(t) -> per-wave LDS bounce -> pa (for PV at body t+1) ---
    #pragma unroll
    for (int nf = 0; nf < 4; nf++){
      __hip_bfloat162 lo, hi;
      lo.x = __float2bfloat16(p[nf][0]); lo.y = __float2bfloat16(p[nf][1]);
      hi.x = __float2bfloat16(p[nf][2]); hi.y = __float2bfloat16(p[nf][3]);
      uint2 pk; pk.x = *(uint32_t*)&lo; pk.y = *(uint32_t*)&hi;
      *(uint2*)((char*)pb + pwb[nf]) = pk;
    }
    asm volatile("s_waitcnt lgkmcnt(0)" ::: "memory");
    #pragma unroll
    for (int c = 0; c < 2; c++)
      pa[c] = *(const bf16x8*)((const char*)pb + prb[c]);

    w = wnext;
    pc = qc; qc = sc;
  }

  // epilogue: PV(31) (pc holds tile 31's buffer after final rotate)
  __builtin_amdgcn_s_setprio(1);
  #pragma unroll
  for (int df = 0; df < 4; df++){
    #pragma unroll
    for (int c = 0; c < 2; c++){
      bf16x8 vf = *(const bf16x8*)&Vs[pc][vaddr[df][c]];
      o[df] = __builtin_amdgcn_mfma_f32_16x16x32_bf16(pa[c], vf, o[df], 0, 0, 0);
    }
  }
  osum = __builtin_amdgcn_mfma_f32_16x16x32_bf16(pa[0], onesb, osum, 0, 0, 0);
  osum = __builtin_amdgcn_mfma_f32_16x16x32_bf16(pa[1], onesb, osum, 0, 0, 0);
  __builtin_amdgcn_s_setprio(0);

  float li[4];
  #pragma unroll
  for (int r = 0; r < 4; r++) li[r] = 1.0f / osum[r];
  #pragma unroll
  for (int df = 0; df < 4; df++){
    #pragma unroll
    for (int r = 0; r < 4; r++){
      int s = q0 + wave*16 + g4 + r;
      int d = h*64 + df*16 + l15;
      AO[((size_t)b*2048 + s)*1024 + d] = f2bf(o[df][r] * li[r]);
    }
  }
}

// ---------------- launch ---------------------------------------------------------
extern "C" void kernel_launch(void* const* d_in, const int* in_sizes, int n_in,
                              void* d_out, int out_size, void* d_ws, size_t ws_size,
                              hipStream_t stream){
  const float* q   = (const float*)d_in[0];
  const float* k   = (const float*)d_in[1];
  const float* v   = (const float*)d_in[2];
  const int*   msk = (const int*)  d_in[3];
  const float* wq  = (const float*)d_in[4];
  const float* wk  = (const float*)d_in[5];
  const float* wv  = (const float*)d_in[6];
  const float* wo  = (const float*)d_in[7];
  const float* bo  = (const float*)d_in[8];

  char* ws = (char*)d_ws;
  ushort_t* conv = (ushort_t*)ws;                 // 33.5 MB of bf16 conversions
  ushort_t* qb  = conv;
  ushort_t* kb  = conv + 4194304;
  ushort_t* vb  = conv + 8388608;
  ushort_t* wqb = conv + 12582912;
  ushort_t* wkb = conv + 13631488;
  ushort_t* wvb = conv + 14680064;
  ushort_t* wob = conv + 15728640;
  u64*      mbits = (u64*)(ws + 33554432);        // 1 MB
  ushort_t* Qh  = (ushort_t*)(ws + 34603008);     // 8 MB
  ushort_t* Kh  = (ushort_t*)(ws + 42991616);     // 8 MB
  // Vt lives in d_out (scratch until gemm_out); must not alias gemm_qkv inputs.
  ushort_t* Vt  = (ushort_t*)d_out;
  ushort_t* AO  = qb;   // qb only read by gemm_qkv z=0 (earlier launch)

  prep_all<<<16384, 256, 0, stream>>>((const float4*)q, (const float4*)k,
      (const float4*)v, (const float4*)wq, (const float4*)wk, (const float4*)wv,
      (const float4*)wo, conv);

  const float qscale = 0.125f * LOG2E;   // fold score scale + log2(e) into Q
  gemm_qkv<<<dim3(32, 8, 4), 256, 0, stream>>>(qb, kb, vb, wqb, wkb, wvb,
                                               Qh, Kh, Vt, qscale,
                                               (const int4*)msk, mbits);

  attn_fused<<<256, 1024, 0, stream>>>(Qh, Kh, Vt, mbits, AO);

  gemm_out<<<dim3(32, 8), 512, 0, stream>>>(AO, wob, (float*)d_out, bo);
}